// Round 6
// baseline (59.772 us; speedup 1.0000x reference)
//
#include <hip/hip_runtime.h>

// MotionResidualBranch — collapsed-linear formulation, 2 kernels.
//
// The whole pipeline is linear in 15 per-(b,t) scalars. Folded tables:
//   G[j][i][e] (i<15), G[j][15][e] = H[j] (WM_b path), base[e];
//   coef[b,t,0..14] = scalars, coef[b,t,15] = 1 (0 on pad rows t=-1,T):
//   U_pw[b,t,e] = base[e] + sum_{j,i} coef[b,t-1+j,i]*G[j][i][e]  + LayerNorm.
//
// r5 post-mortem fixes:
//  - table blocks: wave-dot (coalesced 1KB row reads + shfl butterfly)
//    instead of thread-per-e strided reads (64 txn/instr -> 16).
//  - kb: row-centric accumulation into acc[16] (each coef row s_loaded once,
//    used 3x), then ONE LDS-transpose LayerNorm (2 barriers, 8 shuffles
//    total) instead of per-t reduce (16 barriers, 192 shuffles).

#define DD 256
#define KK 54
#define BB 8
#define TT 1024
#define NCOEF 15
#define CROW 16          // padded coef row (64B)
#define TROWS (TT + 2)   // zero row before t=0 and after t=TT-1
#define TS 16
#define NBT (BB * TT)

// ---------- K_A: blocks 0..48 -> tables ; blocks 49..560 -> coef ----------
__global__ __launch_bounds__(256) void ka_tables_coef(
    const float* __restrict__ barX, const float* __restrict__ W,
    const float* __restrict__ phi_v_w, const float* __restrict__ phi_v_b,
    const float* __restrict__ phi_a_w, const float* __restrict__ phi_a_b,
    const float* __restrict__ gamma_v, const float* __restrict__ gamma_a,
    const float* __restrict__ WM_w, const float* __restrict__ WM_b,
    const float* __restrict__ dw_w, const float* __restrict__ dw_b,
    const float* __restrict__ pw_w, const float* __restrict__ pw_b,
    float* __restrict__ Gt, float* __restrict__ baset, float* __restrict__ coef)
{
  const int tid  = threadIdx.x;
  const int wave = tid >> 6, lane = tid & 63;
  __shared__ __align__(16) float sA[DD];
  __shared__ __align__(16) float cvec[DD];
  __shared__ float wsl[4][64 * 5];

  if (blockIdx.x < 49) {
    // ---- tables, wave-dot (coalesced row reads + butterfly reduce) ----
    const int o = blockIdx.x;            // o = j*16+i (i<15: G, i==15: H); 48: base
    if (o < 48) {
      const int j = o >> 4, i = o & 15;
      if (i < 15) {
        const int p = i / 5, q = i - p * 5;
        float v;
        if (q == 4) v = gamma_v[0] * phi_v_b[tid] + gamma_a[0] * phi_a_b[tid];
        else { const float* phi = (q < 2) ? phi_v_w : phi_a_w; v = phi[tid * 2 + (q & 1)]; }
        sA[tid] = v;
        __syncthreads();
        const float4 ph = ((const float4*)sA)[lane];
        for (int r = 0; r < 64; ++r) {
          const int d = wave * 64 + r;
          const float4 wv = *(const float4*)(WM_w + (size_t)d * (3 * DD) + p * DD + lane * 4);
          float s = wv.x * ph.x + wv.y * ph.y + wv.z * ph.z + wv.w * ph.w;
#pragma unroll
          for (int m = 32; m; m >>= 1) s += __shfl_xor(s, m);
          if (lane == 0) cvec[d] = dw_w[d * 3 + j] * s;
        }
      } else {
        cvec[tid] = dw_w[tid * 3 + j] * WM_b[tid];
      }
    } else {
      cvec[tid] = dw_b[tid];
    }
    __syncthreads();
    const float4 cv = ((const float4*)cvec)[lane];
    for (int r = 0; r < 64; ++r) {
      const int e = wave * 64 + r;
      const float4 pv = *(const float4*)(pw_w + (size_t)e * DD + lane * 4);
      float s = pv.x * cv.x + pv.y * cv.y + pv.z * cv.z + pv.w * cv.w;
#pragma unroll
      for (int m = 32; m; m >>= 1) s += __shfl_xor(s, m);
      if (lane == 0) {
        if (o < 48) Gt[o * DD + e] = s;
        else        baset[e] = s + pw_b[e];
      }
    }
  } else {
    // ---- coef: 16 rows per block, 4 rounds of 4 waves (wave-local LDS) ----
    const int blk  = blockIdx.x - 49;      // 0..511
    const int base = blk * 16;
    const float gv = gamma_v[0], ga = gamma_a[0];
    float* lds = wsl[wave];
    for (int r = 0; r < 4; ++r) {
      const int bt = base + r * 4 + wave;
      const int t  = bt & (TT - 1);
      const int b  = bt >> 10;
      float w = 0.f, v0 = 0.f, v1 = 0.f, a0 = 0.f, a1 = 0.f;
      if (lane < KK) {
        w = W[(size_t)bt * KK + lane];
        const float2* xp = (const float2*)barX + ((size_t)bt * KK + lane);
        const float2 x = xp[0];
        float2 xm = make_float2(0.f, 0.f), xmm = make_float2(0.f, 0.f);
        if (t >= 1) xm  = xp[-KK];
        if (t >= 2) xmm = xp[-2 * KK];
        v0 = x.x - xm.x; v1 = x.y - xm.y;
        const float vm0 = (t >= 1) ? (xm.x - xmm.x) : 0.f;
        const float vm1 = (t >= 1) ? (xm.y - xmm.y) : 0.f;
        a0 = v0 - vm0; a1 = v1 - vm1;
      }
      float wsum = w;
#pragma unroll
      for (int m = 32; m; m >>= 1) wsum += __shfl_xor(wsum, m);
      const float wn = w * (1.f / (wsum + 1e-6f));
      lds[lane * 5 + 0] = wn * v0; lds[lane * 5 + 1] = wn * v1;
      lds[lane * 5 + 2] = wn * a0; lds[lane * 5 + 3] = wn * a1;
      lds[lane * 5 + 4] = wn;
      // wave-synchronous LDS (only this wave touches wsl[wave])
      if (lane < CROW) {
        float accv;
        if (lane == NCOEF) {
          accv = 1.0f;                      // validity flag -> H term
        } else {
          const int p = lane / 5, q = lane - p * 5;
          const int k0 = (p == 0) ? 0  : ((p == 1) ? 12 : 33);
          const int k1 = (p == 0) ? 12 : ((p == 1) ? 33 : 54);
          accv = 0.f;
          for (int k = k0; k < k1; ++k) accv += lds[k * 5 + q];
          if (q < 2) accv *= gv; else if (q < 4) accv *= ga;
        }
        coef[((size_t)b * TROWS + 1 + t) * CROW + lane] = accv;
      }
    }
    // zero pad rows: first 16 coef-blocks each write one
    if (blk < 2 * BB && tid < CROW) {
      const int b = blk >> 1, side = blk & 1;
      coef[((size_t)b * TROWS + (side ? (TT + 1) : 0)) * CROW + tid] = 0.f;
    }
  }
}

// ---------- K_B: row-centric 48-FMA (scalar operands) + transposed LN ----------
__global__ __launch_bounds__(256, 1) void kb_main(
    const float* __restrict__ coef, const float* __restrict__ Gt,
    const float* __restrict__ baset, const float* __restrict__ ln_w,
    const float* __restrict__ ln_b, float* __restrict__ out)
{
  const int b  = blockIdx.x >> 6;
  const int t0 = (blockIdx.x & 63) * TS;
  const int e  = threadIdx.x;

  float Gr[48];
#pragma unroll
  for (int o = 0; o < 48; ++o) Gr[o] = Gt[o * DD + e];
  const float bs = baset[e];
  const float lw = ln_w[e], lb = ln_b[e];

  float acc[TS];
#pragma unroll
  for (int tl = 0; tl < TS; ++tl) acc[tl] = bs;

  // rows r=0..17 <-> coef slots t0+r (slot t0+r = time t0+r-1; pad rows are 0)
  const int rowbase = (b * TROWS + t0) * CROW;
#pragma unroll
  for (int r = 0; r < TS + 2; ++r) {
    const int off = __builtin_amdgcn_readfirstlane(rowbase + r * CROW);
    const float* cr = coef + off;        // SGPR (scalar) loads, K$-resident
    const int tlo = (r - 2 > 0) ? (r - 2) : 0;
    const int thi = (r < TS - 1) ? r : (TS - 1);
#pragma unroll
    for (int tl = tlo; tl <= thi; ++tl) {
      const int j = r - tl;              // 0..2, compile-time after unroll
#pragma unroll
      for (int i = 0; i < CROW; ++i)
        acc[tl] += cr[i] * Gr[j * CROW + i];
    }
  }

  // ---- LayerNorm via one LDS transpose: 2 barriers, 8 shuffles total ----
  __shared__ float aT[TS][DD + 1];       // +1 pad breaks power-of-2 banks
  __shared__ float musd[TS][2];
#pragma unroll
  for (int tl = 0; tl < TS; ++tl) aT[tl][e] = acc[tl];
  __syncthreads();
  {
    const int tg = e >> 4, g = e & 15;   // thread group tg owns t-row tg
    float s = 0.f, ss = 0.f;
#pragma unroll
    for (int k = 0; k < 16; ++k) {
      const float v = aT[tg][g * 16 + ((k + g) & 15)];  // rotated -> ~2-way banks
      s += v; ss += v * v;
    }
#pragma unroll
    for (int m = 8; m; m >>= 1) { s += __shfl_xor(s, m); ss += __shfl_xor(ss, m); }
    if (g == 0) {
      const float mu  = s * (1.f / DD);
      const float var = ss * (1.f / DD) - mu * mu;
      musd[tg][0] = mu;
      musd[tg][1] = rsqrtf(var + 1e-5f);
    }
  }
  __syncthreads();
#pragma unroll
  for (int tl = 0; tl < TS; ++tl) {
    const float mu = musd[tl][0], rs = musd[tl][1];   // wave-uniform broadcast
    out[((size_t)b * TT + t0 + tl) * DD + e] = (acc[tl] - mu) * rs * lw + lb;
  }
}

extern "C" void kernel_launch(void* const* d_in, const int* in_sizes, int n_in,
                              void* d_out, int out_size, void* d_ws, size_t ws_size,
                              hipStream_t stream) {
  const float* barX    = (const float*)d_in[0];
  const float* W       = (const float*)d_in[1];
  const float* phi_v_w = (const float*)d_in[2];
  const float* phi_v_b = (const float*)d_in[3];
  const float* phi_a_w = (const float*)d_in[4];
  const float* phi_a_b = (const float*)d_in[5];
  const float* gamma_v = (const float*)d_in[6];
  const float* gamma_a = (const float*)d_in[7];
  const float* WM_w    = (const float*)d_in[8];
  const float* WM_b    = (const float*)d_in[9];
  const float* dw_w    = (const float*)d_in[10];
  const float* dw_b    = (const float*)d_in[11];
  const float* pw_w    = (const float*)d_in[12];
  const float* pw_b    = (const float*)d_in[13];
  const float* ln_w    = (const float*)d_in[14];
  const float* ln_b    = (const float*)d_in[15];
  float* out = (float*)d_out;

  float* ws    = (float*)d_ws;
  float* Gt    = ws;            // 48*256 = 12288
  float* baset = ws + 12288;    // 256
  float* coef  = ws + 16384;    // 8*1026*16 = 131328 floats

  hipLaunchKernelGGL(ka_tables_coef, dim3(49 + NBT / 16), dim3(256), 0, stream,
                     barX, W, phi_v_w, phi_v_b, phi_a_w, phi_a_b,
                     gamma_v, gamma_a, WM_w, WM_b, dw_w, dw_b, pw_w, pw_b,
                     Gt, baset, coef);
  hipLaunchKernelGGL(kb_main, dim3(BB * (TT / TS)), dim3(256), 0, stream,
                     coef, Gt, baset, ln_w, ln_b, out);
}

// Round 7
// 42.548 us; speedup vs baseline: 1.4048x; 1.4048x over previous
//
#include <hip/hip_runtime.h>

// MotionResidualBranch — collapsed-linear formulation, 3 kernels.
//
// Pipeline is linear in 15 per-(b,t) scalars. Folded tables:
//   A[o][d], o=j*16+i: dw_w[d][j]*mfold[i][d] (i<15), dw_w[d][j]*WM_b[d]
//   (i==15), dw_b[d] (o==48);   Gt[o][e] = sum_d A[o][d]*pw_w[e][d];
//   coef[b,t,0..14]=scalars, coef[b,t,15]=1 (0 on pad rows t=-1,T):
//   U_pw[b,t,e] = base[e] + sum_{j,i} coef[b,t-1+j,i]*Gt[j*16+i][e] + LN.
//
// r6 post-mortem: table dots must be wave-row dots — one 1KB row per
// wave-b128 (16 txn) — with butterflies overlapped across >=5 independent
// accumulators. r5's thread-per-e dots were 64-txn/instr (L1-bound, ~14us);
// r6's serial wave-dot was latency-bound (70us). kb is NOT a bottleneck.

#define DD 256
#define KK 54
#define BB 8
#define TT 1024
#define NCOEF 15
#define CROW 16          // padded coef row (64B)
#define TROWS (TT + 2)   // zero row before t=0 and after t=TT-1
#define TS 16
#define NBT (BB * TT)
#define NT1 48           // T1 blocks: 3 p * 16 d-groups

// ---------- K1: blocks 0..47 -> A table ; blocks 48..2095 -> coef ----------
__global__ __launch_bounds__(256) void k1_A_coef(
    const float* __restrict__ barX, const float* __restrict__ W,
    const float* __restrict__ phi_v_w, const float* __restrict__ phi_v_b,
    const float* __restrict__ phi_a_w, const float* __restrict__ phi_a_b,
    const float* __restrict__ gamma_v, const float* __restrict__ gamma_a,
    const float* __restrict__ WM_w, const float* __restrict__ WM_b,
    const float* __restrict__ dw_w, const float* __restrict__ dw_b,
    float* __restrict__ A, float* __restrict__ coef)
{
  const int tid  = threadIdx.x;
  const int wave = tid >> 6, lane = tid & 63;

  if (blockIdx.x < NT1) {
    // ---- T1: mfold rows for part p, d-group dg (16 d's, 4 per wave) ----
    const int p  = blockIdx.x >> 4;       // 0..2
    const int dg = blockIdx.x & 15;       // 0..15
    const float gv = gamma_v[0], ga = gamma_a[0];
    // per-lane phi values for c = lane*4+k (k=0..3)
    const float4 pv0 = *(const float4*)(phi_v_w + lane * 8);
    const float4 pv1 = *(const float4*)(phi_v_w + lane * 8 + 4);
    const float4 pa0 = *(const float4*)(phi_a_w + lane * 8);
    const float4 pa1 = *(const float4*)(phi_a_w + lane * 8 + 4);
    const float4 pvb = *(const float4*)(phi_v_b + lane * 4);
    const float4 pab = *(const float4*)(phi_a_b + lane * 4);
    // phival[il][k]: il=0 v/q0, 1 v/q1, 2 a/q0, 3 a/q1, 4 bias-comb
    const float f0k[4] = { pv0.x, pv0.z, pv1.x, pv1.z };
    const float f1k[4] = { pv0.y, pv0.w, pv1.y, pv1.w };
    const float f2k[4] = { pa0.x, pa0.z, pa1.x, pa1.z };
    const float f3k[4] = { pa0.y, pa0.w, pa1.y, pa1.w };
    const float f4k[4] = { gv * pvb.x + ga * pab.x, gv * pvb.y + ga * pab.y,
                           gv * pvb.z + ga * pab.z, gv * pvb.w + ga * pab.w };
#pragma unroll
    for (int dd = 0; dd < 4; ++dd) {
      const int d = dg * 16 + wave * 4 + dd;
      const float4 wm = *(const float4*)(WM_w + (size_t)d * (3 * DD) + p * DD + lane * 4);
      float m0 = wm.x * f0k[0] + wm.y * f0k[1] + wm.z * f0k[2] + wm.w * f0k[3];
      float m1 = wm.x * f1k[0] + wm.y * f1k[1] + wm.z * f1k[2] + wm.w * f1k[3];
      float m2 = wm.x * f2k[0] + wm.y * f2k[1] + wm.z * f2k[2] + wm.w * f2k[3];
      float m3 = wm.x * f3k[0] + wm.y * f3k[1] + wm.z * f3k[2] + wm.w * f3k[3];
      float m4 = wm.x * f4k[0] + wm.y * f4k[1] + wm.z * f4k[2] + wm.w * f4k[3];
#pragma unroll
      for (int s = 32; s; s >>= 1) {       // 5-way ILP butterfly
        m0 += __shfl_xor(m0, s); m1 += __shfl_xor(m1, s);
        m2 += __shfl_xor(m2, s); m3 += __shfl_xor(m3, s);
        m4 += __shfl_xor(m4, s);
      }
      if (lane < 15) {
        const int j = lane / 5, il = lane - j * 5;   // o = j*16 + 5p+il
        const float mf = (il == 0) ? m0 : (il == 1) ? m1 : (il == 2) ? m2
                       : (il == 3) ? m3 : m4;
        A[(j * 16 + 5 * p + il) * DD + d] = dw_w[d * 3 + j] * mf;
      }
      if (p == 0) {
        if (lane >= 15 && lane < 18)
          A[((lane - 15) * 16 + 15) * DD + d] = dw_w[d * 3 + (lane - 15)] * WM_b[d];
        if (lane == 18)
          A[48 * DD + d] = dw_b[d];
      }
    }
  } else {
    // ---- coef: one bt row per wave ----
    __shared__ float wsl[4][64 * 5];
    const int blk = blockIdx.x - NT1;     // 0..2047
    const int bt  = blk * 4 + wave;
    const int t   = bt & (TT - 1);
    const int b   = bt >> 10;
    const float gv = gamma_v[0], ga = gamma_a[0];
    float w = 0.f, v0 = 0.f, v1 = 0.f, a0 = 0.f, a1 = 0.f;
    if (lane < KK) {
      w = W[(size_t)bt * KK + lane];
      const float2* xp = (const float2*)barX + ((size_t)bt * KK + lane);
      const float2 x = xp[0];
      float2 xm = make_float2(0.f, 0.f), xmm = make_float2(0.f, 0.f);
      if (t >= 1) xm  = xp[-KK];
      if (t >= 2) xmm = xp[-2 * KK];
      v0 = x.x - xm.x; v1 = x.y - xm.y;
      const float vm0 = (t >= 1) ? (xm.x - xmm.x) : 0.f;
      const float vm1 = (t >= 1) ? (xm.y - xmm.y) : 0.f;
      a0 = v0 - vm0; a1 = v1 - vm1;
    }
    float wsum = w;
#pragma unroll
    for (int m = 32; m; m >>= 1) wsum += __shfl_xor(wsum, m);
    const float wn = w * (1.f / (wsum + 1e-6f));
    float* lds = wsl[wave];
    lds[lane * 5 + 0] = wn * v0; lds[lane * 5 + 1] = wn * v1;
    lds[lane * 5 + 2] = wn * a0; lds[lane * 5 + 3] = wn * a1;
    lds[lane * 5 + 4] = wn;
    // wave-synchronous LDS (wave-local slice; proven pattern r5/r6)
    if (lane < CROW) {
      float accv;
      if (lane == NCOEF) {
        accv = 1.0f;                       // validity flag -> H terms
      } else {
        const int p = lane / 5, q = lane - p * 5;
        const int k0 = (p == 0) ? 0  : ((p == 1) ? 12 : 33);
        const int k1 = (p == 0) ? 12 : ((p == 1) ? 33 : 54);
        accv = 0.f;
        for (int k = k0; k < k1; ++k) accv += lds[k * 5 + q];
        if (q < 2) accv *= gv; else if (q < 4) accv *= ga;
      }
      coef[((size_t)b * TROWS + 1 + t) * CROW + lane] = accv;
    }
    // zero pad rows: first 16 coef-blocks each write one
    if (blk < 2 * BB && tid < CROW) {
      const int bz = blk >> 1, side = blk & 1;
      coef[((size_t)bz * TROWS + (side ? (TT + 1) : 0)) * CROW + tid] = 0.f;
    }
  }
}

// ---------- K2: Gt[o][e] = sum_d A[o][d]*pw_w[e][d] ; wave-per-e ----------
__global__ __launch_bounds__(256) void k2_gt(
    const float* __restrict__ A, const float* __restrict__ pw_w,
    const float* __restrict__ pw_b,
    float* __restrict__ Gt, float* __restrict__ baset)
{
  const int wave = threadIdx.x >> 6, lane = threadIdx.x & 63;
  const int e = blockIdx.x * 4 + wave;
  const float4 Pr = *(const float4*)(pw_w + (size_t)e * DD + lane * 4);
#pragma unroll 7
  for (int o = 0; o < 49; ++o) {
    const float4 a4 = *(const float4*)(A + o * DD + lane * 4);
    float s = a4.x * Pr.x + a4.y * Pr.y + a4.z * Pr.z + a4.w * Pr.w;
#pragma unroll
    for (int m = 32; m; m >>= 1) s += __shfl_xor(s, m);
    if (lane == 0) {
      if (o < 48) Gt[o * DD + e] = s;
      else        baset[e] = s + pw_b[e];
    }
  }
}

// ---------- K3: row-centric 48-FMA (scalar operands) + transposed LN ----------
__global__ __launch_bounds__(256, 1) void k3_main(
    const float* __restrict__ coef, const float* __restrict__ Gt,
    const float* __restrict__ baset, const float* __restrict__ ln_w,
    const float* __restrict__ ln_b, float* __restrict__ out)
{
  const int b  = blockIdx.x >> 6;
  const int t0 = (blockIdx.x & 63) * TS;
  const int e  = threadIdx.x;

  float Gr[48];
#pragma unroll
  for (int o = 0; o < 48; ++o) Gr[o] = Gt[o * DD + e];
  const float bs = baset[e];
  const float lw = ln_w[e], lb = ln_b[e];

  float acc[TS];
#pragma unroll
  for (int tl = 0; tl < TS; ++tl) acc[tl] = bs;

  const int rowbase = (b * TROWS + t0) * CROW;
#pragma unroll
  for (int r = 0; r < TS + 2; ++r) {
    const int off = __builtin_amdgcn_readfirstlane(rowbase + r * CROW);
    const float* cr = coef + off;        // SGPR (scalar) loads, K$-resident
    const int tlo = (r - 2 > 0) ? (r - 2) : 0;
    const int thi = (r < TS - 1) ? r : (TS - 1);
#pragma unroll
    for (int tl = tlo; tl <= thi; ++tl) {
      const int j = r - tl;              // 0..2, compile-time after unroll
#pragma unroll
      for (int i = 0; i < CROW; ++i)
        acc[tl] += cr[i] * Gr[j * CROW + i];
    }
  }

  // LayerNorm via one LDS transpose: 2 barriers, 8 shuffles total
  __shared__ float aT[TS][DD + 1];
  __shared__ float musd[TS][2];
#pragma unroll
  for (int tl = 0; tl < TS; ++tl) aT[tl][e] = acc[tl];
  __syncthreads();
  {
    const int tg = e >> 4, g = e & 15;
    float s = 0.f, ss = 0.f;
#pragma unroll
    for (int k = 0; k < 16; ++k) {
      const float v = aT[tg][g * 16 + ((k + g) & 15)];
      s += v; ss += v * v;
    }
#pragma unroll
    for (int m = 8; m; m >>= 1) { s += __shfl_xor(s, m); ss += __shfl_xor(ss, m); }
    if (g == 0) {
      const float mu  = s * (1.f / DD);
      const float var = ss * (1.f / DD) - mu * mu;
      musd[tg][0] = mu;
      musd[tg][1] = rsqrtf(var + 1e-5f);
    }
  }
  __syncthreads();
#pragma unroll
  for (int tl = 0; tl < TS; ++tl) {
    const float mu = musd[tl][0], rs = musd[tl][1];
    out[((size_t)b * TT + t0 + tl) * DD + e] = (acc[tl] - mu) * rs * lw + lb;
  }
}

extern "C" void kernel_launch(void* const* d_in, const int* in_sizes, int n_in,
                              void* d_out, int out_size, void* d_ws, size_t ws_size,
                              hipStream_t stream) {
  const float* barX    = (const float*)d_in[0];
  const float* W       = (const float*)d_in[1];
  const float* phi_v_w = (const float*)d_in[2];
  const float* phi_v_b = (const float*)d_in[3];
  const float* phi_a_w = (const float*)d_in[4];
  const float* phi_a_b = (const float*)d_in[5];
  const float* gamma_v = (const float*)d_in[6];
  const float* gamma_a = (const float*)d_in[7];
  const float* WM_w    = (const float*)d_in[8];
  const float* WM_b    = (const float*)d_in[9];
  const float* dw_w    = (const float*)d_in[10];
  const float* dw_b    = (const float*)d_in[11];
  const float* pw_w    = (const float*)d_in[12];
  const float* pw_b    = (const float*)d_in[13];
  const float* ln_w    = (const float*)d_in[14];
  const float* ln_b    = (const float*)d_in[15];
  float* out = (float*)d_out;

  float* ws    = (float*)d_ws;
  float* Gt    = ws;              // 48*256 = 12288
  float* baset = ws + 12288;      // 256
  float* coef  = ws + 16384;      // 8*1026*16 = 131328 floats
  float* A     = ws + 16384 + 131328;  // 49*256 = 12544 floats

  hipLaunchKernelGGL(k1_A_coef, dim3(NT1 + NBT / 4), dim3(256), 0, stream,
                     barX, W, phi_v_w, phi_v_b, phi_a_w, phi_a_b,
                     gamma_v, gamma_a, WM_w, WM_b, dw_w, dw_b, A, coef);
  hipLaunchKernelGGL(k2_gt, dim3(64), dim3(256), 0, stream,
                     A, pw_w, pw_b, Gt, baset);
  hipLaunchKernelGGL(k3_main, dim3(BB * (TT / TS)), dim3(256), 0, stream,
                     coef, Gt, baset, ln_w, ln_b, out);
}

// Round 8
// 30.693 us; speedup vs baseline: 1.9474x; 1.3862x over previous
//
#include <hip/hip_runtime.h>

// MotionResidualBranch — collapsed-linear formulation, 2 kernels (r5 proven).
//
// The whole pipeline is linear in 15 per-(b,t) scalars. Folded tables:
//   G[j][i][e] (i<15), G[j][15][e] = H[j] (WM_b path), base[e];
//   coef[b,t,0..14] = scalars, coef[b,t,15] = 1 (0 on pad rows t=-1,T):
//   U_pw[b,t,e] = base[e] + sum_{j,i} coef[b,t-1+j,i]*G[j][i][e]  + LayerNorm.
//
// Round-trajectory evidence: dur ≈ 38 + 4.3us * (n_kernels - 2); the ~38us
// floor coincides with the harness's recurring 256MB fill at ~86% HBM peak.
// 2 kernels with a sub-floor chain is the measured optimum (r5: 38.1us).

#define DD 256
#define KK 54
#define BB 8
#define TT 1024
#define NCOEF 15
#define CROW 16          // padded coef row (64B)
#define TROWS (TT + 2)   // zero row before t=0 and after t=TT-1
#define TS 16
#define NBT (BB * TT)

// ---------- K_A: blocks 0..48 -> tables ; blocks 49..560 -> coef ----------
__global__ __launch_bounds__(256) void ka_tables_coef(
    const float* __restrict__ barX, const float* __restrict__ W,
    const float* __restrict__ phi_v_w, const float* __restrict__ phi_v_b,
    const float* __restrict__ phi_a_w, const float* __restrict__ phi_a_b,
    const float* __restrict__ gamma_v, const float* __restrict__ gamma_a,
    const float* __restrict__ WM_w, const float* __restrict__ WM_b,
    const float* __restrict__ dw_w, const float* __restrict__ dw_b,
    const float* __restrict__ pw_w, const float* __restrict__ pw_b,
    float* __restrict__ Gt, float* __restrict__ baset, float* __restrict__ coef)
{
  const int tid  = threadIdx.x;
  const int wave = tid >> 6, lane = tid & 63;
  __shared__ __align__(16) float sA[DD];
  __shared__ __align__(16) float sB[DD];
  __shared__ float wsl[4][64 * 5];

  if (blockIdx.x < 49) {
    // ---- tables: o = j*16+i (i<15: G via inline mfold; i==15: H), o==48: base
    const int o = blockIdx.x;
    float cv;
    if (o < 48) {
      const int j = o >> 4, i = o & 15;
      if (i < 15) {
        const int p = i / 5, q = i - p * 5;
        float v;
        if (q == 4) v = gamma_v[0] * phi_v_b[tid] + gamma_a[0] * phi_a_b[tid];
        else { const float* phi = (q < 2) ? phi_v_w : phi_a_w; v = phi[tid * 2 + (q & 1)]; }
        sA[tid] = v;
        __syncthreads();
        // mfold[i][tid] = dot(WM_w row tid slice p, sA)
        const float4* wrow = (const float4*)(WM_w + (size_t)tid * (3 * DD) + p * DD);
        const float4* ph   = (const float4*)sA;
        float m = 0.f;
#pragma unroll 8
        for (int c = 0; c < DD / 4; ++c) {
          const float4 a = wrow[c], bq = ph[c];
          m += a.x * bq.x + a.y * bq.y + a.z * bq.z + a.w * bq.w;
        }
        cv = dw_w[tid * 3 + j] * m;
      } else {
        cv = dw_w[tid * 3 + j] * WM_b[tid];
      }
    } else {
      cv = dw_b[tid];
    }
    sB[tid] = cv;
    __syncthreads();
    const float4* prow = (const float4*)(pw_w + (size_t)tid * DD);
    const float4* cp   = (const float4*)sB;
    float acc = 0.f;
#pragma unroll 8
    for (int c = 0; c < DD / 4; ++c) {
      const float4 a = prow[c], bq = cp[c];
      acc += a.x * bq.x + a.y * bq.y + a.z * bq.z + a.w * bq.w;
    }
    if (o < 48) Gt[o * DD + tid] = acc;
    else        baset[tid] = acc + pw_b[tid];
  } else {
    // ---- coef: 16 rows per block, 4 rounds of 4 waves (wave-local LDS) ----
    const int blk  = blockIdx.x - 49;      // 0..511
    const int base = blk * 16;
    const float gv = gamma_v[0], ga = gamma_a[0];
    float* lds = wsl[wave];
    for (int r = 0; r < 4; ++r) {
      const int bt = base + r * 4 + wave;
      const int t  = bt & (TT - 1);
      const int b  = bt >> 10;
      float w = 0.f, v0 = 0.f, v1 = 0.f, a0 = 0.f, a1 = 0.f;
      if (lane < KK) {
        w = W[(size_t)bt * KK + lane];
        const float2* xp = (const float2*)barX + ((size_t)bt * KK + lane);
        const float2 x = xp[0];
        float2 xm = make_float2(0.f, 0.f), xmm = make_float2(0.f, 0.f);
        if (t >= 1) xm  = xp[-KK];
        if (t >= 2) xmm = xp[-2 * KK];
        v0 = x.x - xm.x; v1 = x.y - xm.y;
        const float vm0 = (t >= 1) ? (xm.x - xmm.x) : 0.f;
        const float vm1 = (t >= 1) ? (xm.y - xmm.y) : 0.f;
        a0 = v0 - vm0; a1 = v1 - vm1;
      }
      float wsum = w;
#pragma unroll
      for (int m = 32; m; m >>= 1) wsum += __shfl_xor(wsum, m);
      const float wn = w * (1.f / (wsum + 1e-6f));
      lds[lane * 5 + 0] = wn * v0; lds[lane * 5 + 1] = wn * v1;
      lds[lane * 5 + 2] = wn * a0; lds[lane * 5 + 3] = wn * a1;
      lds[lane * 5 + 4] = wn;
      // wave-synchronous LDS (only this wave touches wsl[wave])
      if (lane < CROW) {
        float accv;
        if (lane == NCOEF) {
          accv = 1.0f;                      // validity flag -> H term
        } else {
          const int p = lane / 5, q = lane - p * 5;
          const int k0 = (p == 0) ? 0  : ((p == 1) ? 12 : 33);
          const int k1 = (p == 0) ? 12 : ((p == 1) ? 33 : 54);
          accv = 0.f;
          for (int k = k0; k < k1; ++k) accv += lds[k * 5 + q];
          if (q < 2) accv *= gv; else if (q < 4) accv *= ga;
        }
        coef[((size_t)b * TROWS + 1 + t) * CROW + lane] = accv;
      }
    }
    // zero pad rows: first 16 coef-blocks each write one
    if (blk < 2 * BB && tid < CROW) {
      const int b = blk >> 1, side = blk & 1;
      coef[((size_t)b * TROWS + (side ? (TT + 1) : 0)) * CROW + tid] = 0.f;
    }
  }
}

// ---------- K_B: row-centric 48-FMA (scalar operands) + transposed LN ----------
__global__ __launch_bounds__(256, 1) void kb_main(
    const float* __restrict__ coef, const float* __restrict__ Gt,
    const float* __restrict__ baset, const float* __restrict__ ln_w,
    const float* __restrict__ ln_b, float* __restrict__ out)
{
  const int b  = blockIdx.x >> 6;
  const int t0 = (blockIdx.x & 63) * TS;
  const int e  = threadIdx.x;

  float Gr[48];
#pragma unroll
  for (int o = 0; o < 48; ++o) Gr[o] = Gt[o * DD + e];
  const float bs = baset[e];
  const float lw = ln_w[e], lb = ln_b[e];

  float acc[TS];
#pragma unroll
  for (int tl = 0; tl < TS; ++tl) acc[tl] = bs;

  // rows r=0..17 <-> coef slots t0+r (slot t0+r = time t0+r-1; pad rows are 0)
  const int rowbase = (b * TROWS + t0) * CROW;
#pragma unroll
  for (int r = 0; r < TS + 2; ++r) {
    const int off = __builtin_amdgcn_readfirstlane(rowbase + r * CROW);
    const float* cr = coef + off;        // SGPR (scalar) loads, K$-resident
    const int tlo = (r - 2 > 0) ? (r - 2) : 0;
    const int thi = (r < TS - 1) ? r : (TS - 1);
#pragma unroll
    for (int tl = tlo; tl <= thi; ++tl) {
      const int j = r - tl;              // 0..2, compile-time after unroll
#pragma unroll
      for (int i = 0; i < CROW; ++i)
        acc[tl] += cr[i] * Gr[j * CROW + i];
    }
  }

  // ---- LayerNorm via one LDS transpose: 2 barriers, 8 shuffles total ----
  __shared__ float aT[TS][DD + 1];       // +1 pad breaks power-of-2 banks
  __shared__ float musd[TS][2];
#pragma unroll
  for (int tl = 0; tl < TS; ++tl) aT[tl][e] = acc[tl];
  __syncthreads();
  {
    const int tg = e >> 4, g = e & 15;   // thread group tg owns t-row tg
    float s = 0.f, ss = 0.f;
#pragma unroll
    for (int k = 0; k < 16; ++k) {
      const float v = aT[tg][g * 16 + ((k + g) & 15)];  // rotated -> ~2-way banks
      s += v; ss += v * v;
    }
#pragma unroll
    for (int m = 8; m; m >>= 1) { s += __shfl_xor(s, m); ss += __shfl_xor(ss, m); }
    if (g == 0) {
      const float mu  = s * (1.f / DD);
      const float var = ss * (1.f / DD) - mu * mu;
      musd[tg][0] = mu;
      musd[tg][1] = rsqrtf(var + 1e-5f);
    }
  }
  __syncthreads();
#pragma unroll
  for (int tl = 0; tl < TS; ++tl) {
    const float mu = musd[tl][0], rs = musd[tl][1];   // wave-uniform broadcast
    out[((size_t)b * TT + t0 + tl) * DD + e] = (acc[tl] - mu) * rs * lw + lb;
  }
}

extern "C" void kernel_launch(void* const* d_in, const int* in_sizes, int n_in,
                              void* d_out, int out_size, void* d_ws, size_t ws_size,
                              hipStream_t stream) {
  const float* barX    = (const float*)d_in[0];
  const float* W       = (const float*)d_in[1];
  const float* phi_v_w = (const float*)d_in[2];
  const float* phi_v_b = (const float*)d_in[3];
  const float* phi_a_w = (const float*)d_in[4];
  const float* phi_a_b = (const float*)d_in[5];
  const float* gamma_v = (const float*)d_in[6];
  const float* gamma_a = (const float*)d_in[7];
  const float* WM_w    = (const float*)d_in[8];
  const float* WM_b    = (const float*)d_in[9];
  const float* dw_w    = (const float*)d_in[10];
  const float* dw_b    = (const float*)d_in[11];
  const float* pw_w    = (const float*)d_in[12];
  const float* pw_b    = (const float*)d_in[13];
  const float* ln_w    = (const float*)d_in[14];
  const float* ln_b    = (const float*)d_in[15];
  float* out = (float*)d_out;

  float* ws    = (float*)d_ws;
  float* Gt    = ws;            // 48*256 = 12288
  float* baset = ws + 12288;    // 256
  float* coef  = ws + 16384;    // 8*1026*16 = 131328 floats

  hipLaunchKernelGGL(ka_tables_coef, dim3(49 + NBT / 16), dim3(256), 0, stream,
                     barX, W, phi_v_w, phi_v_b, phi_a_w, phi_a_b,
                     gamma_v, gamma_a, WM_w, WM_b, dw_w, dw_b, pw_w, pw_b,
                     Gt, baset, coef);
  hipLaunchKernelGGL(kb_main, dim3(BB * (TT / TS)), dim3(256), 0, stream,
                     coef, Gt, baset, ln_w, ln_b, out);
}